// Round 1
// baseline (234.994 us; speedup 1.0000x reference)
//
#include <hip/hip_runtime.h>
#include <math.h>

#define SS 14
#define NCLS 20
#define CELL_FLOATS 30

__device__ __forceinline__ float smooth_l1(float d) {
    float ad = fabsf(d);
    return ad < 1.0f ? 0.5f * d * d : ad - 0.5f;
}

__device__ __forceinline__ void conv_box(const float* b, float gi, float gj,
                                         float& x, float& y, float& w, float& h) {
    const float STEP = 1.0f / 14.0f;
    x = fmaxf((b[0] + gi) * STEP - b[2] * 0.5f, 0.0f);
    y = fmaxf((b[1] + gj) * STEP - b[3] * 0.5f, 0.0f);
    w = fmaxf(b[2], 0.0f);
    h = fmaxf(b[3], 0.0f);
}

__device__ __forceinline__ float iou_box(float x1, float y1, float w1, float h1,
                                         float x2, float y2, float w2, float h2) {
    float iw = fmaxf(w1 + w2 - (fmaxf(x1 + w1, x2 + w2) - fminf(x1, x2)), 0.0f);
    float ih = fmaxf(h1 + h2 - (fmaxf(y1 + h1, y2 + h2) - fminf(y1, y2)), 0.0f);
    float inter = iw * ih;
    float uni = w1 * h1 + w2 * h2 - inter;
    return inter / (uni + 1e-6f);
}

__global__ void zero_out_kernel(float* out) { out[0] = 0.0f; }

__global__ __launch_bounds__(256) void yolo_loss_kernel(
    const float* __restrict__ pred, const float* __restrict__ target,
    float* __restrict__ out, int ncells, float inv_batch) {
    int cell = blockIdx.x * blockDim.x + threadIdx.x;
    float tot = 0.0f;
    if (cell < ncells) {
        float p[CELL_FLOATS], t[CELL_FLOATS];
        const float2* pp = (const float2*)(pred + (size_t)cell * CELL_FLOATS);
        const float2* tp = (const float2*)(target + (size_t)cell * CELL_FLOATS);
#pragma unroll
        for (int k = 0; k < CELL_FLOATS / 2; ++k) {
            ((float2*)p)[k] = pp[k];
            ((float2*)t)[k] = tp[k];
        }

        int rc = cell % (SS * SS);
        float gj = (float)(rc / SS);   // axis 1 index -> gj
        float gi = (float)(rc % SS);   // axis 2 index -> gi

        // IoUs for the two boxes
        float px, py, pw, ph, tx, ty, tw, th;
        conv_box(p + 0, gi, gj, px, py, pw, ph);
        conv_box(t + 0, gi, gj, tx, ty, tw, th);
        float iou0 = iou_box(px, py, pw, ph, tx, ty, tw, th);
        conv_box(p + 5, gi, gj, px, py, pw, ph);
        conv_box(t + 5, gi, gj, tx, ty, tw, th);
        float iou1 = iou_box(px, py, pw, ph, tx, ty, tw, th);

        bool obj0 = t[4] > 0.0f;
        bool obj1 = t[9] > 0.0f;
        bool sig = obj1;                 // sig_mask = obj_mask[..., 1]
        bool m1 = iou1 > iou0;           // argmax (tie -> 0)
        bool om0 = sig ? (obj0 && !m1) : obj0;
        bool om1 = sig ? m1 : false;     // in else branch obj1 == false

        float c0 = p[4] - t[4]; c0 *= c0;
        float c1 = p[9] - t[9]; c1 *= c1;
        float obj_l = (om0 ? c0 : 0.0f) + (om1 ? c1 : 0.0f);
        float noobj_l = (om0 ? 0.0f : c0) + (om1 ? 0.0f : c1);

        float xy = 0.0f, wh = 0.0f;
        if (om0) {
            xy += smooth_l1(p[0] - t[0]) + smooth_l1(p[1] - t[1]);
            wh += smooth_l1(sqrtf(fmaxf(p[2], 1e-6f)) - sqrtf(fmaxf(t[2], 1e-6f)));
            wh += smooth_l1(sqrtf(fmaxf(p[3], 1e-6f)) - sqrtf(fmaxf(t[3], 1e-6f)));
        }
        if (om1) {
            xy += smooth_l1(p[5] - t[5]) + smooth_l1(p[6] - t[6]);
            wh += smooth_l1(sqrtf(fmaxf(p[7], 1e-6f)) - sqrtf(fmaxf(t[7], 1e-6f)));
            wh += smooth_l1(sqrtf(fmaxf(p[8], 1e-6f)) - sqrtf(fmaxf(t[8], 1e-6f)));
        }

        // class NLL (log_softmax over 20), masked by sig
        float cls = 0.0f;
        {
            float m = p[10];
#pragma unroll
            for (int c = 1; c < NCLS; ++c) m = fmaxf(m, p[10 + c]);
            float se = 0.0f;
#pragma unroll
            for (int c = 0; c < NCLS; ++c) se += expf(p[10 + c] - m);
            float bt = t[10];
            int bi = 0;
#pragma unroll
            for (int c = 1; c < NCLS; ++c) {
                if (t[10 + c] > bt) { bt = t[10 + c]; bi = c; }
            }
            float logp = p[10 + bi] - m - logf(se);
            cls = sig ? -logp : 0.0f;
        }

        tot = 3.0f * (xy + wh) + obj_l + 0.3f * noobj_l + 1.5f * cls;
        tot *= inv_batch;
    }

    // wave-64 reduction
#pragma unroll
    for (int off = 32; off > 0; off >>= 1) tot += __shfl_down(tot, off, 64);
    __shared__ float wsum[4];
    int lane = threadIdx.x & 63;
    int wid = threadIdx.x >> 6;
    if (lane == 0) wsum[wid] = tot;
    __syncthreads();
    if (threadIdx.x == 0) {
        float s = wsum[0] + wsum[1] + wsum[2] + wsum[3];
        atomicAdd(out, s);
    }
}

extern "C" void kernel_launch(void* const* d_in, const int* in_sizes, int n_in,
                              void* d_out, int out_size, void* d_ws, size_t ws_size,
                              hipStream_t stream) {
    const float* pred = (const float*)d_in[0];
    const float* target = (const float*)d_in[1];
    float* out = (float*)d_out;

    int total = in_sizes[0];
    int ncells = total / CELL_FLOATS;
    int batch = ncells / (SS * SS);
    float inv_batch = 1.0f / (float)batch;

    zero_out_kernel<<<1, 1, 0, stream>>>(out);
    int block = 256;
    int grid = (ncells + block - 1) / block;
    yolo_loss_kernel<<<grid, block, 0, stream>>>(pred, target, out, ncells, inv_batch);
}

// Round 2
// 234.227 us; speedup vs baseline: 1.0033x; 1.0033x over previous
//
#include <hip/hip_runtime.h>
#include <math.h>

#define SS 14
#define NCLS 20
#define CELL_FLOATS 30
#define BLOCK 256
#define CELLS_PER_BLOCK 256
// floats per block per array
#define FPB (CELLS_PER_BLOCK * CELL_FLOATS)     // 7680 floats = 30720 B
#define F4PB (FPB / 4)                           // 1920 float4

__device__ __forceinline__ float smooth_l1(float d) {
    float ad = fabsf(d);
    return ad < 1.0f ? 0.5f * d * d : ad - 0.5f;
}

__device__ __forceinline__ void conv_box(const float* b, float gi, float gj,
                                         float& x, float& y, float& w, float& h) {
    const float STEP = 1.0f / 14.0f;
    x = fmaxf((b[0] + gi) * STEP - b[2] * 0.5f, 0.0f);
    y = fmaxf((b[1] + gj) * STEP - b[3] * 0.5f, 0.0f);
    w = fmaxf(b[2], 0.0f);
    h = fmaxf(b[3], 0.0f);
}

__device__ __forceinline__ float iou_box(float x1, float y1, float w1, float h1,
                                         float x2, float y2, float w2, float h2) {
    float iw = fmaxf(w1 + w2 - (fmaxf(x1 + w1, x2 + w2) - fminf(x1, x2)), 0.0f);
    float ih = fmaxf(h1 + h2 - (fmaxf(y1 + h1, y2 + h2) - fminf(y1, y2)), 0.0f);
    float inter = iw * ih;
    float uni = w1 * h1 + w2 * h2 - inter;
    return inter / (uni + 1e-6f);
}

__global__ void zero_out_kernel(float* out) { out[0] = 0.0f; }

__global__ __launch_bounds__(BLOCK) void yolo_loss_kernel(
    const float4* __restrict__ pred4, const float4* __restrict__ target4,
    float* __restrict__ out, int ncells, float inv_batch) {
    __shared__ float sp[FPB];
    __shared__ float st[FPB];

    const int tid = threadIdx.x;
    const int cell0 = blockIdx.x * CELLS_PER_BLOCK;
    const long long total4 = ((long long)ncells * CELL_FLOATS) / 4;
    const long long base4 = (long long)blockIdx.x * F4PB;

    // coalesced staging: 1920 float4 per array, 256 threads
#pragma unroll
    for (int k = 0; k < 8; ++k) {
        int i = tid + k * BLOCK;
        if (i < F4PB && base4 + i < total4) {
            ((float4*)sp)[i] = pred4[base4 + i];
            ((float4*)st)[i] = target4[base4 + i];
        }
    }
    __syncthreads();

    int cell = cell0 + tid;
    float tot = 0.0f;
    if (cell < ncells) {
        float p[CELL_FLOATS], t[CELL_FLOATS];
        const float2* pp = (const float2*)(sp + tid * CELL_FLOATS);
        const float2* tp = (const float2*)(st + tid * CELL_FLOATS);
#pragma unroll
        for (int k = 0; k < CELL_FLOATS / 2; ++k) {
            ((float2*)p)[k] = pp[k];
            ((float2*)t)[k] = tp[k];
        }

        int rc = cell % (SS * SS);
        float gj = (float)(rc / SS);   // axis 1 index -> gj
        float gi = (float)(rc % SS);   // axis 2 index -> gi

        float px, py, pw, ph, tx, ty, tw, th;
        conv_box(p + 0, gi, gj, px, py, pw, ph);
        conv_box(t + 0, gi, gj, tx, ty, tw, th);
        float iou0 = iou_box(px, py, pw, ph, tx, ty, tw, th);
        conv_box(p + 5, gi, gj, px, py, pw, ph);
        conv_box(t + 5, gi, gj, tx, ty, tw, th);
        float iou1 = iou_box(px, py, pw, ph, tx, ty, tw, th);

        bool obj0 = t[4] > 0.0f;
        bool obj1 = t[9] > 0.0f;
        bool sig = obj1;                 // sig_mask = obj_mask[..., 1]
        bool m1 = iou1 > iou0;           // argmax (tie -> 0)
        bool om0 = sig ? (obj0 && !m1) : obj0;
        bool om1 = sig ? m1 : false;

        float c0 = p[4] - t[4]; c0 *= c0;
        float c1 = p[9] - t[9]; c1 *= c1;
        float obj_l = (om0 ? c0 : 0.0f) + (om1 ? c1 : 0.0f);
        float noobj_l = (om0 ? 0.0f : c0) + (om1 ? 0.0f : c1);

        float xy = 0.0f, wh = 0.0f;
        if (om0) {
            xy += smooth_l1(p[0] - t[0]) + smooth_l1(p[1] - t[1]);
            wh += smooth_l1(sqrtf(fmaxf(p[2], 1e-6f)) - sqrtf(fmaxf(t[2], 1e-6f)));
            wh += smooth_l1(sqrtf(fmaxf(p[3], 1e-6f)) - sqrtf(fmaxf(t[3], 1e-6f)));
        }
        if (om1) {
            xy += smooth_l1(p[5] - t[5]) + smooth_l1(p[6] - t[6]);
            wh += smooth_l1(sqrtf(fmaxf(p[7], 1e-6f)) - sqrtf(fmaxf(t[7], 1e-6f)));
            wh += smooth_l1(sqrtf(fmaxf(p[8], 1e-6f)) - sqrtf(fmaxf(t[8], 1e-6f)));
        }

        float cls = 0.0f;
        {
            float m = p[10];
#pragma unroll
            for (int c = 1; c < NCLS; ++c) m = fmaxf(m, p[10 + c]);
            float se = 0.0f;
#pragma unroll
            for (int c = 0; c < NCLS; ++c) se += expf(p[10 + c] - m);
            float bt = t[10];
            int bi = 0;
#pragma unroll
            for (int c = 1; c < NCLS; ++c) {
                if (t[10 + c] > bt) { bt = t[10 + c]; bi = c; }
            }
            float logp = p[10 + bi] - m - logf(se);
            cls = sig ? -logp : 0.0f;
        }

        tot = 3.0f * (xy + wh) + obj_l + 0.3f * noobj_l + 1.5f * cls;
        tot *= inv_batch;
    }

    // wave-64 reduction
#pragma unroll
    for (int off = 32; off > 0; off >>= 1) tot += __shfl_down(tot, off, 64);
    __shared__ float wsum[4];
    int lane = threadIdx.x & 63;
    int wid = threadIdx.x >> 6;
    if (lane == 0) wsum[wid] = tot;
    __syncthreads();
    if (threadIdx.x == 0) {
        float s = wsum[0] + wsum[1] + wsum[2] + wsum[3];
        atomicAdd(out, s);
    }
}

extern "C" void kernel_launch(void* const* d_in, const int* in_sizes, int n_in,
                              void* d_out, int out_size, void* d_ws, size_t ws_size,
                              hipStream_t stream) {
    const float4* pred4 = (const float4*)d_in[0];
    const float4* target4 = (const float4*)d_in[1];
    float* out = (float*)d_out;

    int total = in_sizes[0];
    int ncells = total / CELL_FLOATS;
    int batch = ncells / (SS * SS);
    float inv_batch = 1.0f / (float)batch;

    zero_out_kernel<<<1, 1, 0, stream>>>(out);
    int grid = (ncells + CELLS_PER_BLOCK - 1) / CELLS_PER_BLOCK;
    yolo_loss_kernel<<<grid, BLOCK, 0, stream>>>(pred4, target4, out, ncells, inv_batch);
}

// Round 3
// 230.910 us; speedup vs baseline: 1.0177x; 1.0144x over previous
//
#include <hip/hip_runtime.h>
#include <math.h>

#define SS 14
#define NCLS 20
#define CELL_FLOATS 30
#define BLOCK 256
#define CPB 128                       // cells per block
#define FPB (CPB * CELL_FLOATS)       // 3840 floats = 15360 B per array
#define F4PB (FPB / 4)                // 960 float4 per array

__device__ __forceinline__ float smooth_l1(float d) {
    float ad = fabsf(d);
    return ad < 1.0f ? 0.5f * d * d : ad - 0.5f;
}

__device__ __forceinline__ void conv_box(const float* b, float gi, float gj,
                                         float& x, float& y, float& w, float& h) {
    const float STEP = 1.0f / 14.0f;
    x = fmaxf((b[0] + gi) * STEP - b[2] * 0.5f, 0.0f);
    y = fmaxf((b[1] + gj) * STEP - b[3] * 0.5f, 0.0f);
    w = fmaxf(b[2], 0.0f);
    h = fmaxf(b[3], 0.0f);
}

__device__ __forceinline__ float iou_box(float x1, float y1, float w1, float h1,
                                         float x2, float y2, float w2, float h2) {
    float iw = fmaxf(w1 + w2 - (fmaxf(x1 + w1, x2 + w2) - fminf(x1, x2)), 0.0f);
    float ih = fmaxf(h1 + h2 - (fmaxf(y1 + h1, y2 + h2) - fminf(y1, y2)), 0.0f);
    float inter = iw * ih;
    float uni = w1 * h1 + w2 * h2 - inter;
    return inter / (uni + 1e-6f);
}

__global__ __launch_bounds__(BLOCK) void yolo_loss_kernel(
    const float4* __restrict__ pred4, const float4* __restrict__ target4,
    float* __restrict__ partials, int ncells, float inv_batch) {
    __shared__ float sp[FPB];
    __shared__ float st[FPB];

    const int tid = threadIdx.x;
    const long long total4 = ((long long)ncells * CELL_FLOATS) / 4;
    const long long base4 = (long long)blockIdx.x * F4PB;

    // coalesced staging: 960 float4 per array, 256 threads (3.75 each)
#pragma unroll
    for (int k = 0; k < 4; ++k) {
        int i = tid + k * BLOCK;
        if (i < F4PB && base4 + i < total4) {
            ((float4*)sp)[i] = pred4[base4 + i];
            ((float4*)st)[i] = target4[base4 + i];
        }
    }
    __syncthreads();

    int cell = blockIdx.x * CPB + tid;
    float tot = 0.0f;
    if (tid < CPB && cell < ncells) {
        float p[CELL_FLOATS], t[CELL_FLOATS];
        const float2* pp = (const float2*)(sp + tid * CELL_FLOATS);
        const float2* tp = (const float2*)(st + tid * CELL_FLOATS);
#pragma unroll
        for (int k = 0; k < CELL_FLOATS / 2; ++k) {
            ((float2*)p)[k] = pp[k];
            ((float2*)t)[k] = tp[k];
        }

        int rc = cell % (SS * SS);
        float gj = (float)(rc / SS);   // axis 1 index
        float gi = (float)(rc % SS);   // axis 2 index

        float px, py, pw, ph, tx, ty, tw, th;
        conv_box(p + 0, gi, gj, px, py, pw, ph);
        conv_box(t + 0, gi, gj, tx, ty, tw, th);
        float iou0 = iou_box(px, py, pw, ph, tx, ty, tw, th);
        conv_box(p + 5, gi, gj, px, py, pw, ph);
        conv_box(t + 5, gi, gj, tx, ty, tw, th);
        float iou1 = iou_box(px, py, pw, ph, tx, ty, tw, th);

        bool obj0 = t[4] > 0.0f;
        bool obj1 = t[9] > 0.0f;
        bool sig = obj1;                 // sig_mask = obj_mask[..., 1]
        bool m1 = iou1 > iou0;           // argmax (tie -> 0)
        bool om0 = sig ? (obj0 && !m1) : obj0;
        bool om1 = sig ? m1 : false;

        float c0 = p[4] - t[4]; c0 *= c0;
        float c1 = p[9] - t[9]; c1 *= c1;
        float obj_l = (om0 ? c0 : 0.0f) + (om1 ? c1 : 0.0f);
        float noobj_l = (om0 ? 0.0f : c0) + (om1 ? 0.0f : c1);

        float xy = 0.0f, wh = 0.0f;
        if (om0) {
            xy += smooth_l1(p[0] - t[0]) + smooth_l1(p[1] - t[1]);
            wh += smooth_l1(sqrtf(fmaxf(p[2], 1e-6f)) - sqrtf(fmaxf(t[2], 1e-6f)));
            wh += smooth_l1(sqrtf(fmaxf(p[3], 1e-6f)) - sqrtf(fmaxf(t[3], 1e-6f)));
        }
        if (om1) {
            xy += smooth_l1(p[5] - t[5]) + smooth_l1(p[6] - t[6]);
            wh += smooth_l1(sqrtf(fmaxf(p[7], 1e-6f)) - sqrtf(fmaxf(t[7], 1e-6f)));
            wh += smooth_l1(sqrtf(fmaxf(p[8], 1e-6f)) - sqrtf(fmaxf(t[8], 1e-6f)));
        }

        float cls = 0.0f;
        {
            float m = p[10];
#pragma unroll
            for (int c = 1; c < NCLS; ++c) m = fmaxf(m, p[10 + c]);
            float se = 0.0f;
#pragma unroll
            for (int c = 0; c < NCLS; ++c) se += expf(p[10 + c] - m);
            float bt = t[10];
            int bi = 0;
#pragma unroll
            for (int c = 1; c < NCLS; ++c) {
                if (t[10 + c] > bt) { bt = t[10 + c]; bi = c; }
            }
            float logp = p[10 + bi] - m - logf(se);
            cls = sig ? -logp : 0.0f;
        }

        tot = 3.0f * (xy + wh) + obj_l + 0.3f * noobj_l + 1.5f * cls;
        tot *= inv_batch;
    }

    // wave-64 reduction, then per-block plain store (NO contended atomic)
#pragma unroll
    for (int off = 32; off > 0; off >>= 1) tot += __shfl_down(tot, off, 64);
    __shared__ float wsum[4];
    int lane = threadIdx.x & 63;
    int wid = threadIdx.x >> 6;
    if (lane == 0) wsum[wid] = tot;
    __syncthreads();
    if (threadIdx.x == 0) {
        partials[blockIdx.x] = wsum[0] + wsum[1] + wsum[2] + wsum[3];
    }
}

__global__ __launch_bounds__(BLOCK) void reduce_kernel(
    const float* __restrict__ partials, float* __restrict__ out, int n) {
    float s = 0.0f;
    for (int i = threadIdx.x; i < n; i += BLOCK) s += partials[i];
#pragma unroll
    for (int off = 32; off > 0; off >>= 1) s += __shfl_down(s, off, 64);
    __shared__ float wsum[4];
    int lane = threadIdx.x & 63;
    int wid = threadIdx.x >> 6;
    if (lane == 0) wsum[wid] = s;
    __syncthreads();
    if (threadIdx.x == 0) out[0] = wsum[0] + wsum[1] + wsum[2] + wsum[3];
}

extern "C" void kernel_launch(void* const* d_in, const int* in_sizes, int n_in,
                              void* d_out, int out_size, void* d_ws, size_t ws_size,
                              hipStream_t stream) {
    const float4* pred4 = (const float4*)d_in[0];
    const float4* target4 = (const float4*)d_in[1];
    float* out = (float*)d_out;
    float* partials = (float*)d_ws;

    int total = in_sizes[0];
    int ncells = total / CELL_FLOATS;
    int batch = ncells / (SS * SS);
    float inv_batch = 1.0f / (float)batch;

    int grid = (ncells + CPB - 1) / CPB;
    yolo_loss_kernel<<<grid, BLOCK, 0, stream>>>(pred4, target4, partials, ncells, inv_batch);
    reduce_kernel<<<1, BLOCK, 0, stream>>>(partials, out, grid);
}